// Round 2
// baseline (3109.034 us; speedup 1.0000x reference)
//
#include <hip/hip_runtime.h>
#include <hip/hip_bf16.h>

// ---------------------------------------------------------------------------
// VoxelBackBone8x: 12 sparse 3D conv layers, each followed by global BN+ReLU.
// R2: register-tiled gather conv. Thread = 4 points x 4 couts (16 acc regs).
// Weights read as float4 over cout (shared across points), features as float4
// over cin (each scalar reused across 4 couts). ~10x fewer VMEM instructions
// than R1's thread=(point,cout) version, which was VMEM-issue bound
// (VALUBusy 15%, HBM 0.7%, layer6/7 at 767us each).
// ---------------------------------------------------------------------------

__global__ __launch_bounds__(256) void scatter_grid(const int* __restrict__ coords, int n,
                                                    int* __restrict__ grid, int D, int H, int W) {
    int i = blockIdx.x * blockDim.x + threadIdx.x;
    if (i >= n) return;
    const int b = coords[4*i+0], z = coords[4*i+1], y = coords[4*i+2], x = coords[4*i+3];
    grid[(((size_t)b*D + z)*H + y)*W + x] = i;
}

template<int CIN, int COUT, int KD, int KH, int KW>
__global__ __launch_bounds__(256) void sp_conv(
    const float* __restrict__ fin, const int* __restrict__ grid,
    const int* __restrict__ oc, int n_out,
    const float* __restrict__ w, float* __restrict__ out,
    int D, int H, int W, int sz, int sy, int sx, int pz, int py, int px)
{
    constexpr int TPP = COUT / 4;        // threads per point (4 couts each)
    constexpr int PGR = 256 / TPP;       // point-groups per block
    constexpr int PPT = 4;               // points per thread
    const int cg = threadIdx.x % TPP;
    const int pg = threadIdx.x / TPP;
    const int pbase = (blockIdx.x * PGR + pg) * PPT;

    int iz0[PPT], iy0[PPT], ix0[PPT];
    const int* gb[PPT];
    bool live[PPT];
#pragma unroll
    for (int k = 0; k < PPT; ++k) {
        const int p = pbase + k;
        live[k] = (p < n_out);
        int4 cc = live[k] ? ((const int4*)oc)[p] : make_int4(0,0,0,0);
        gb[k]  = grid + (size_t)cc.x * D * H * W;
        iz0[k] = cc.y * sz - pz;
        iy0[k] = cc.z * sy - py;
        ix0[k] = cc.w * sx - px;
    }

    float acc[PPT][4];
#pragma unroll
    for (int k = 0; k < PPT; ++k) { acc[k][0]=0.f; acc[k][1]=0.f; acc[k][2]=0.f; acc[k][3]=0.f; }

    for (int kd = 0; kd < KD; ++kd)
    for (int kh = 0; kh < KH; ++kh)
    for (int kw = 0; kw < KW; ++kw) {
        int idx[PPT];
        bool any = false;
#pragma unroll
        for (int k = 0; k < PPT; ++k) {
            const int iz = iz0[k] + kd, iy = iy0[k] + kh, ix = ix0[k] + kw;
            const bool ok = live[k] && (unsigned)iz < (unsigned)D &&
                            (unsigned)iy < (unsigned)H && (unsigned)ix < (unsigned)W;
            idx[k] = ok ? gb[k][((size_t)iz*H + iy)*W + ix] : -1;
            any |= (idx[k] >= 0);
        }
        if (!any) continue;

        const float4* wq = (const float4*)(w + ((size_t)((kd*KH + kh)*KW + kw) * CIN) * COUT) + cg;

#pragma unroll 4
        for (int q = 0; q < CIN/4; ++q) {
            float4 f[PPT];
#pragma unroll
            for (int k = 0; k < PPT; ++k) {
                f[k] = (idx[k] >= 0)
                     ? ((const float4*)(fin + (size_t)idx[k] * CIN))[q]
                     : make_float4(0.f, 0.f, 0.f, 0.f);
            }
#pragma unroll
            for (int j = 0; j < 4; ++j) {
                const float4 w4 = wq[(size_t)(4*q + j) * (COUT/4)];
#pragma unroll
                for (int k = 0; k < PPT; ++k) {
                    const float s = (j == 0) ? f[k].x : (j == 1) ? f[k].y : (j == 2) ? f[k].z : f[k].w;
                    acc[k][0] = fmaf(s, w4.x, acc[k][0]);
                    acc[k][1] = fmaf(s, w4.y, acc[k][1]);
                    acc[k][2] = fmaf(s, w4.z, acc[k][2]);
                    acc[k][3] = fmaf(s, w4.w, acc[k][3]);
                }
            }
        }
    }

#pragma unroll
    for (int k = 0; k < PPT; ++k) {
        const int p = pbase + k;
        if (p < n_out) {
            float4 o;
            o.x = acc[k][0]; o.y = acc[k][1]; o.z = acc[k][2]; o.w = acc[k][3];
            ((float4*)(out + (size_t)p * COUT))[cg] = o;
        }
    }
}

template<int C>
__global__ __launch_bounds__(256) void reduce_stats(const float* __restrict__ x, int n,
                                                    float* __restrict__ stats)
{
    constexpr int R = 256 / C;
    __shared__ float s1[256];
    __shared__ float s2[256];
    const int c = threadIdx.x % C;
    const int r = threadIdx.x / C;
    float a1 = 0.f, a2 = 0.f;
    for (int i = blockIdx.x * R + r; i < n; i += R * gridDim.x) {
        float v = x[(size_t)i*C + c];
        a1 += v;
        a2 += v * v;
    }
    s1[threadIdx.x] = a1;
    s2[threadIdx.x] = a2;
    __syncthreads();
    for (int off = 128; off >= C; off >>= 1) {
        if (threadIdx.x < off) {
            s1[threadIdx.x] += s1[threadIdx.x + off];
            s2[threadIdx.x] += s2[threadIdx.x + off];
        }
        __syncthreads();
    }
    if (threadIdx.x < C) {
        atomicAdd(&stats[c],     s1[threadIdx.x]);
        atomicAdd(&stats[C + c], s2[threadIdx.x]);
    }
}

template<int C>
__global__ __launch_bounds__(256) void bn_relu_apply(const float* __restrict__ x,
                                                     float* __restrict__ y, int n,
                                                     const float* __restrict__ stats,
                                                     const float* __restrict__ gamma,
                                                     const float* __restrict__ beta)
{
    const size_t i = (size_t)blockIdx.x * blockDim.x + threadIdx.x;
    if (i >= (size_t)n * C) return;
    const int c = (int)(i % C);
    const float inv_n = 1.f / (float)n;
    const float mu  = stats[c] * inv_n;
    const float var = stats[C + c] * inv_n - mu * mu;
    const float g = gamma[c] * rsqrtf(var + 1e-3f);
    const float v = (x[i] - mu) * g + beta[c];
    y[i] = v > 0.f ? v : 0.f;
}

extern "C" void kernel_launch(void* const* d_in, const int* in_sizes, int n_in,
                              void* d_out, int out_size, void* d_ws, size_t ws_size,
                              hipStream_t stream) {
    const float* vf    = (const float*)d_in[0];
    const float* w_in  = (const float*)d_in[1];
    const float* w1    = (const float*)d_in[2];
    const float* w2_0  = (const float*)d_in[3];
    const float* w2_1  = (const float*)d_in[4];
    const float* w2_2  = (const float*)d_in[5];
    const float* w3_0  = (const float*)d_in[6];
    const float* w3_1  = (const float*)d_in[7];
    const float* w3_2  = (const float*)d_in[8];
    const float* w4_0  = (const float*)d_in[9];
    const float* w4_1  = (const float*)d_in[10];
    const float* w4_2  = (const float*)d_in[11];
    const float* w_out = (const float*)d_in[12];
    const float* gamma = (const float*)d_in[13];
    const float* beta  = (const float*)d_in[14];
    const int* c1 = (const int*)d_in[15];
    const int* c2 = (const int*)d_in[16];
    const int* c3 = (const int*)d_in[17];
    const int* c4 = (const int*)d_in[18];
    const int* c5 = (const int*)d_in[19];
    const int N1 = in_sizes[15] / 4;
    const int N2 = in_sizes[16] / 4;
    const int N3 = in_sizes[17] / 4;
    const int N4 = in_sizes[18] / 4;
    const int N5 = in_sizes[19] / 4;

    // workspace layout
    const size_t G1 = (size_t)2*41*160*160;
    const size_t G2 = (size_t)2*21*80*80;
    const size_t G3 = (size_t)2*11*40*40;
    const size_t G4 = (size_t)2*5*20*20;
    int* grid1 = (int*)d_ws;
    int* grid2 = grid1 + G1;
    int* grid3 = grid2 + G2;
    int* grid4 = grid3 + G3;
    float* stats = (float*)(grid4 + G4);          // 12 layers x 256 floats
    float* bufA  = stats + 12*256;
    size_t maxE = (size_t)N1*16;
    if ((size_t)N2*32  > maxE) maxE = (size_t)N2*32;
    if ((size_t)N3*64  > maxE) maxE = (size_t)N3*64;
    if ((size_t)N4*64  > maxE) maxE = (size_t)N4*64;
    if ((size_t)N5*128 > maxE) maxE = (size_t)N5*128;
    maxE = (maxE + 3) & ~(size_t)3;
    float* bufB = bufA + maxE;

    hipMemsetAsync(grid1, 0xFF, (G1+G2+G3+G4)*sizeof(int), stream);
    hipMemsetAsync(stats, 0, 12*256*sizeof(float), stream);

    scatter_grid<<<(N1+255)/256, 256, 0, stream>>>(c1, N1, grid1, 41,160,160);
    scatter_grid<<<(N2+255)/256, 256, 0, stream>>>(c2, N2, grid2, 21, 80, 80);
    scatter_grid<<<(N3+255)/256, 256, 0, stream>>>(c3, N3, grid3, 11, 40, 40);
    scatter_grid<<<(N4+255)/256, 256, 0, stream>>>(c4, N4, grid4,  5, 20, 20);

#define LAYER(i, CIN, COUT, KD, KH, KW, FIN, GRD, OC, NP, WP, RAW, FOUT, D,H,W, SZ,SY,SX, PZ,PY,PX, GOFF) \
    { \
        constexpr int PPB_ = (256 / ((COUT)/4)) * 4;  /* points per block */ \
        sp_conv<CIN,COUT,KD,KH,KW><<<((NP)+PPB_-1)/PPB_, 256, 0, stream>>>( \
            FIN, GRD, OC, NP, WP, RAW, D,H,W, SZ,SY,SX, PZ,PY,PX); \
        constexpr int R_ = 256 / (COUT); \
        int rb = ((NP) + R_ - 1) / R_; if (rb > 240) rb = 240; if (rb < 1) rb = 1; \
        reduce_stats<COUT><<<rb, 256, 0, stream>>>(RAW, NP, stats + (i)*256); \
        bn_relu_apply<COUT><<<((size_t)(NP)*(COUT) + 255)/256, 256, 0, stream>>>( \
            RAW, FOUT, NP, stats + (i)*256, gamma + (GOFF), beta + (GOFF)); \
    }

    LAYER( 0,  4, 16, 3,3,3, vf,   grid1, c1, N1, w_in,  bufA, bufA, 41,160,160, 1,1,1, 1,1,1,   0);
    LAYER( 1, 16, 16, 3,3,3, bufA, grid1, c1, N1, w1,    bufB, bufB, 41,160,160, 1,1,1, 1,1,1,  16);
    LAYER( 2, 16, 32, 3,3,3, bufB, grid1, c2, N2, w2_0,  bufA, bufA, 41,160,160, 2,2,2, 1,1,1,  32);
    LAYER( 3, 32, 32, 3,3,3, bufA, grid2, c2, N2, w2_1,  bufB, bufB, 21, 80, 80, 1,1,1, 1,1,1,  64);
    LAYER( 4, 32, 32, 3,3,3, bufB, grid2, c2, N2, w2_2,  bufA, bufA, 21, 80, 80, 1,1,1, 1,1,1,  96);
    LAYER( 5, 32, 64, 3,3,3, bufA, grid2, c3, N3, w3_0,  bufB, bufB, 21, 80, 80, 2,2,2, 1,1,1, 128);
    LAYER( 6, 64, 64, 3,3,3, bufB, grid3, c3, N3, w3_1,  bufA, bufA, 11, 40, 40, 1,1,1, 1,1,1, 192);
    LAYER( 7, 64, 64, 3,3,3, bufA, grid3, c3, N3, w3_2,  bufB, bufB, 11, 40, 40, 1,1,1, 1,1,1, 256);
    LAYER( 8, 64, 64, 3,3,3, bufB, grid3, c4, N4, w4_0,  bufA, bufA, 11, 40, 40, 2,2,2, 0,1,1, 320);
    LAYER( 9, 64, 64, 3,3,3, bufA, grid4, c4, N4, w4_1,  bufB, bufB,  5, 20, 20, 1,1,1, 1,1,1, 384);
    LAYER(10, 64, 64, 3,3,3, bufB, grid4, c4, N4, w4_2,  bufA, bufA,  5, 20, 20, 1,1,1, 1,1,1, 448);
    LAYER(11, 64,128, 3,1,1, bufA, grid4, c5, N5, w_out, bufB, (float*)d_out,
                                                                 5, 20, 20, 2,1,1, 0,0,0, 512);
#undef LAYER
}

// Round 3
// 733.793 us; speedup vs baseline: 4.2369x; 4.2369x over previous
//
#include <hip/hip_runtime.h>
#include <hip/hip_bf16.h>

// ---------------------------------------------------------------------------
// VoxelBackBone8x, R3: bf16 MFMA implicit-GEMM sparse conv.
// Per tap: out[p,:] += feat[idx(p,tap),:] @ W[tap]  as 16x16x32 bf16 MFMA.
// Weights pre-transposed to bf16 [tap][cout][cin] (B-frag: lane n reads 8
// contiguous cin). A-frag: lane gathers 8 contiguous bf16 from feat[idx].
// Verified layouts (learn_hip m89/m91/m120):
//   A[m=lane&15][k=quad*8+j], B[n=lane&15][k=quad*8+j],
//   C/D col=lane&15, row=quad*4+reg.
// Conv outputs fp32 raw -> reduce stats -> BN+ReLU writes bf16 (next layer)
// or fp32 (final). Layer 0 (CIN=4) stays on a VALU kernel.
// ---------------------------------------------------------------------------

typedef __attribute__((ext_vector_type(8))) short bf16x8;
typedef __attribute__((ext_vector_type(4))) float f32x4;

__device__ inline unsigned short f2bf(float f) {
    unsigned u = __builtin_bit_cast(unsigned, f);
    u += 0x7FFFu + ((u >> 16) & 1u);
    return (unsigned short)(u >> 16);
}

__global__ __launch_bounds__(256) void scatter_grid(const int* __restrict__ coords, int n,
                                                    int* __restrict__ grid, int D, int H, int W) {
    int i = blockIdx.x * blockDim.x + threadIdx.x;
    if (i >= n) return;
    const int b = coords[4*i+0], z = coords[4*i+1], y = coords[4*i+2], x = coords[4*i+3];
    grid[(((size_t)b*D + z)*H + y)*W + x] = i;
}

// fp32 [t][cin][cout] -> bf16 [t][cout][cin], pad taps T..TP-1 zeroed
__global__ __launch_bounds__(256) void prep_w(const float* __restrict__ w,
                                              unsigned short* __restrict__ wt,
                                              int T, int TP, int CIN, int COUT) {
    int i = blockIdx.x * 256 + threadIdx.x;
    int total = TP * CIN * COUT;
    if (i >= total) return;
    int co = i % COUT; int r = i / COUT; int ci = r % CIN; int t = r / CIN;
    unsigned short v = (t < T) ? f2bf(w[i]) : (unsigned short)0;
    wt[((size_t)t * COUT + co) * CIN + ci] = v;
}

// Layer 0: CIN=4 -> COUT=16, k=3, stride 1, pad 1, fp32 VALU
__global__ __launch_bounds__(256) void sp_conv0(const float* __restrict__ fin,
                                                const int* __restrict__ grid,
                                                const int* __restrict__ oc, int n_out,
                                                const float* __restrict__ w,
                                                float* __restrict__ out,
                                                int D, int H, int W) {
    const int c = threadIdx.x & 15;
    const int p = (blockIdx.x * 256 + threadIdx.x) >> 4;
    if (p >= n_out) return;
    const int b   = oc[4*p+0];
    const int iz0 = oc[4*p+1] - 1;
    const int iy0 = oc[4*p+2] - 1;
    const int ix0 = oc[4*p+3] - 1;
    const int* gb = grid + (size_t)b * D * H * W;
    float acc = 0.f;
    for (int kd = 0; kd < 3; ++kd) {
        const int iz = iz0 + kd;
        if ((unsigned)iz >= (unsigned)D) continue;
        for (int kh = 0; kh < 3; ++kh) {
            const int iy = iy0 + kh;
            if ((unsigned)iy >= (unsigned)H) continue;
            for (int kw = 0; kw < 3; ++kw) {
                const int ix = ix0 + kw;
                if ((unsigned)ix >= (unsigned)W) continue;
                const int idx = gb[((size_t)iz*H + iy)*W + ix];
                if (idx < 0) continue;
                const float4 v = *(const float4*)(fin + (size_t)idx * 4);
                const float* wp = w + (size_t)((kd*3 + kh)*3 + kw) * 4 * 16 + c;
                acc = fmaf(v.x, wp[0],  acc);
                acc = fmaf(v.y, wp[16], acc);
                acc = fmaf(v.z, wp[32], acc);
                acc = fmaf(v.w, wp[48], acc);
            }
        }
    }
    out[(size_t)p*16 + c] = acc;
}

template<int CIN, int COUT, int KD, int KH, int KW>
__global__ __launch_bounds__(256) void sp_conv_mfma(
    const unsigned short* __restrict__ fin, const int* __restrict__ grid,
    const int* __restrict__ oc, int n_out,
    const unsigned short* __restrict__ wt, float* __restrict__ out,
    int D, int H, int W, int sz, int sy, int sx, int pz, int py, int px)
{
    constexpr int T  = KD*KH*KW;
    constexpr int NT = COUT/16;
    const int lane = threadIdx.x & 63;
    const int wid  = threadIdx.x >> 6;
    const int n    = lane & 15;
    const int quad = lane >> 4;
    const int pbase = blockIdx.x * 64 + wid * 16;

    int pc = pbase + n;
    if (pc > n_out - 1) pc = n_out - 1;
    const int4 cc = ((const int4*)oc)[pc];
    const int* gb = grid + (size_t)cc.x * D * H * W;
    const int iz0 = cc.y * sz - pz;
    const int iy0 = cc.z * sy - py;
    const int ix0 = cc.w * sx - px;

    f32x4 acc[NT];
#pragma unroll
    for (int t = 0; t < NT; ++t) acc[t] = (f32x4){0.f, 0.f, 0.f, 0.f};

    if constexpr (CIN >= 32) {
        for (int tap = 0; tap < T; ++tap) {
            const int kd = tap / (KH*KW), kr = tap % (KH*KW), kh = kr / KW, kw = kr % KW;
            const int iz = iz0 + kd, iy = iy0 + kh, ix = ix0 + kw;
            int idx = -1;
            if ((unsigned)iz < (unsigned)D && (unsigned)iy < (unsigned)H && (unsigned)ix < (unsigned)W)
                idx = gb[((size_t)iz*H + iy)*W + ix];
            const unsigned short* wrow = wt + (size_t)tap * COUT * CIN;
#pragma unroll
            for (int s = 0; s < CIN/32; ++s) {
                const int cinb = s*32 + quad*8;
                bf16x8 a = {};
                if (idx >= 0) a = *(const bf16x8*)(fin + (size_t)idx * CIN + cinb);
#pragma unroll
                for (int t = 0; t < NT; ++t) {
                    bf16x8 b = *(const bf16x8*)(wrow + (size_t)(t*16 + n) * CIN + cinb);
                    acc[t] = __builtin_amdgcn_mfma_f32_16x16x32_bf16(a, b, acc[t], 0, 0, 0);
                }
            }
        }
    } else {  // CIN == 16: pack 2 taps per K=32 mfma (quad pairs pick the tap)
        constexpr int KB = (T + 1) / 2;
        for (int kb = 0; kb < KB; ++kb) {
            const int tap = 2*kb + (quad >> 1);
            const bool tv = (tap < T);
            const int tc = tv ? tap : T;    // pad slot (zeroed by prep_w)
            const int td = tv ? tap : 0;
            const int kd = td / (KH*KW), kr = td % (KH*KW), kh = kr / KW, kw = kr % KW;
            const int iz = iz0 + kd, iy = iy0 + kh, ix = ix0 + kw;
            int idx = -1;
            if (tv && (unsigned)iz < (unsigned)D && (unsigned)iy < (unsigned)H && (unsigned)ix < (unsigned)W)
                idx = gb[((size_t)iz*H + iy)*W + ix];
            const int cinb = (quad & 1) * 8;
            bf16x8 a = {};
            if (idx >= 0) a = *(const bf16x8*)(fin + (size_t)idx * CIN + cinb);
#pragma unroll
            for (int t = 0; t < NT; ++t) {
                bf16x8 b = *(const bf16x8*)(wt + ((size_t)tc * COUT + t*16 + n) * CIN + cinb);
                acc[t] = __builtin_amdgcn_mfma_f32_16x16x32_bf16(a, b, acc[t], 0, 0, 0);
            }
        }
    }

#pragma unroll
    for (int t = 0; t < NT; ++t) {
#pragma unroll
        for (int r = 0; r < 4; ++r) {
            const int p = pbase + quad*4 + r;
            if (p < n_out) out[(size_t)p * COUT + t*16 + n] = acc[t][r];
        }
    }
}

template<int C>
__global__ __launch_bounds__(256) void reduce_stats(const float* __restrict__ x, int nn,
                                                    float* __restrict__ stats)
{
    constexpr int R = 256 / C;
    __shared__ float s1[256];
    __shared__ float s2[256];
    const int c = threadIdx.x % C;
    const int r = threadIdx.x / C;
    float a1 = 0.f, a2 = 0.f;
    for (int i = blockIdx.x * R + r; i < nn; i += R * gridDim.x) {
        float v = x[(size_t)i*C + c];
        a1 += v;
        a2 += v * v;
    }
    s1[threadIdx.x] = a1;
    s2[threadIdx.x] = a2;
    __syncthreads();
    for (int off = 128; off >= C; off >>= 1) {
        if (threadIdx.x < off) {
            s1[threadIdx.x] += s1[threadIdx.x + off];
            s2[threadIdx.x] += s2[threadIdx.x + off];
        }
        __syncthreads();
    }
    if (threadIdx.x < C) {
        atomicAdd(&stats[c],     s1[threadIdx.x]);
        atomicAdd(&stats[C + c], s2[threadIdx.x]);
    }
}

__device__ inline void stv(float* p, float v)          { *p = v; }
__device__ inline void stv(unsigned short* p, float v) { *p = f2bf(v); }

template<int C, typename OUT>
__global__ __launch_bounds__(256) void bn_relu_apply(const float* __restrict__ x,
                                                     OUT* __restrict__ y, int nn,
                                                     const float* __restrict__ stats,
                                                     const float* __restrict__ gamma,
                                                     const float* __restrict__ beta)
{
    const size_t i = (size_t)blockIdx.x * blockDim.x + threadIdx.x;
    if (i >= (size_t)nn * C) return;
    const int c = (int)(i % C);
    const float inv_n = 1.f / (float)nn;
    const float mu  = stats[c] * inv_n;
    const float var = stats[C + c] * inv_n - mu * mu;
    const float g = gamma[c] * rsqrtf(var + 1e-3f);
    const float v = (x[i] - mu) * g + beta[c];
    stv(y + i, v > 0.f ? v : 0.f);
}

extern "C" void kernel_launch(void* const* d_in, const int* in_sizes, int n_in,
                              void* d_out, int out_size, void* d_ws, size_t ws_size,
                              hipStream_t stream) {
    const float* WPTR[12] = {
        (const float*)d_in[1], (const float*)d_in[2], (const float*)d_in[3],
        (const float*)d_in[4], (const float*)d_in[5], (const float*)d_in[6],
        (const float*)d_in[7], (const float*)d_in[8], (const float*)d_in[9],
        (const float*)d_in[10], (const float*)d_in[11], (const float*)d_in[12] };
    const float* vf    = (const float*)d_in[0];
    const float* gamma = (const float*)d_in[13];
    const float* beta  = (const float*)d_in[14];
    const int* c1 = (const int*)d_in[15];
    const int* c2 = (const int*)d_in[16];
    const int* c3 = (const int*)d_in[17];
    const int* c4 = (const int*)d_in[18];
    const int* c5 = (const int*)d_in[19];
    const int N1 = in_sizes[15] / 4;
    const int N2 = in_sizes[16] / 4;
    const int N3 = in_sizes[17] / 4;
    const int N4 = in_sizes[18] / 4;
    const int N5 = in_sizes[19] / 4;

    static const int LT[12]  = {27,27,27,27,27,27,27,27,27,27,27,3};
    static const int LCI[12] = {4,16,16,32,32,32,64,64,64,64,64,64};
    static const int LCO[12] = {16,16,32,32,32,64,64,64,64,64,64,128};

    const size_t G1 = (size_t)2*41*160*160;
    const size_t G2 = (size_t)2*21*80*80;
    const size_t G3 = (size_t)2*11*40*40;
    const size_t G4 = (size_t)2*5*20*20;
    int* grid1 = (int*)d_ws;
    int* grid2 = grid1 + G1;
    int* grid3 = grid2 + G2;
    int* grid4 = grid3 + G3;
    float* stats = (float*)(grid4 + G4);            // 12 x 256 floats

    size_t maxE = (size_t)N1*16;
    if ((size_t)N2*32  > maxE) maxE = (size_t)N2*32;
    if ((size_t)N3*64  > maxE) maxE = (size_t)N3*64;
    if ((size_t)N4*64  > maxE) maxE = (size_t)N4*64;
    if ((size_t)N5*128 > maxE) maxE = (size_t)N5*128;
    maxE = (maxE + 7) & ~(size_t)7;

    float* raw = stats + 12*256;                    // fp32 conv output
    unsigned short* fA = (unsigned short*)(raw + maxE);
    unsigned short* fB = fA + maxE;
    unsigned short* wtb = fB + maxE;                // bf16 transposed weights
    size_t wtoff[12];
    {
        size_t o = 0;
        for (int i = 1; i < 12; ++i) {
            wtoff[i] = o;
            o += (size_t)(LT[i] + 1) * LCI[i] * LCO[i];
        }
    }

    hipMemsetAsync(grid1, 0xFF, (G1+G2+G3+G4)*sizeof(int), stream);
    hipMemsetAsync(stats, 0, 12*256*sizeof(float), stream);

    scatter_grid<<<(N1+255)/256, 256, 0, stream>>>(c1, N1, grid1, 41,160,160);
    scatter_grid<<<(N2+255)/256, 256, 0, stream>>>(c2, N2, grid2, 21, 80, 80);
    scatter_grid<<<(N3+255)/256, 256, 0, stream>>>(c3, N3, grid3, 11, 40, 40);
    scatter_grid<<<(N4+255)/256, 256, 0, stream>>>(c4, N4, grid4,  5, 20, 20);

    for (int i = 1; i < 12; ++i) {
        int total = (LT[i] + 1) * LCI[i] * LCO[i];
        prep_w<<<(total + 255)/256, 256, 0, stream>>>(WPTR[i], wtb + wtoff[i],
                                                      LT[i], LT[i] + 1, LCI[i], LCO[i]);
    }

#define BNSTAGE(i, COUT, NP, FOUT_T, FOUT) \
    { \
        constexpr int R_ = 256 / (COUT); \
        int rb = ((NP) + R_ - 1) / R_; if (rb > 240) rb = 240; if (rb < 1) rb = 1; \
        reduce_stats<COUT><<<rb, 256, 0, stream>>>(raw, NP, stats + (i)*256); \
        bn_relu_apply<COUT, FOUT_T><<<(((size_t)(NP)*(COUT)) + 255)/256, 256, 0, stream>>>( \
            raw, FOUT, NP, stats + (i)*256, gamma + GOFF_##i, beta + GOFF_##i); \
    }
    enum { GOFF_0 = 0, GOFF_1 = 16, GOFF_2 = 32, GOFF_3 = 64, GOFF_4 = 96, GOFF_5 = 128,
           GOFF_6 = 192, GOFF_7 = 256, GOFF_8 = 320, GOFF_9 = 384, GOFF_10 = 448, GOFF_11 = 512 };

    // L0: fp32 VALU conv
    sp_conv0<<<((size_t)N1*16 + 255)/256, 256, 0, stream>>>(vf, grid1, c1, N1, WPTR[0], raw, 41,160,160);
    BNSTAGE(0, 16, N1, unsigned short, fA);

#define CONV(i, CIN, COUT, KD,KH,KW, FIN, GRD, OC, NP, D,H,W, SZ,SY,SX, PZ,PY,PX) \
    sp_conv_mfma<CIN,COUT,KD,KH,KW><<<((NP)+63)/64, 256, 0, stream>>>( \
        FIN, GRD, OC, NP, wtb + wtoff[i], raw, D,H,W, SZ,SY,SX, PZ,PY,PX);

    CONV( 1, 16, 16, 3,3,3, fA, grid1, c1, N1, 41,160,160, 1,1,1, 1,1,1); BNSTAGE( 1, 16, N1, unsigned short, fB);
    CONV( 2, 16, 32, 3,3,3, fB, grid1, c2, N2, 41,160,160, 2,2,2, 1,1,1); BNSTAGE( 2, 32, N2, unsigned short, fA);
    CONV( 3, 32, 32, 3,3,3, fA, grid2, c2, N2, 21, 80, 80, 1,1,1, 1,1,1); BNSTAGE( 3, 32, N2, unsigned short, fB);
    CONV( 4, 32, 32, 3,3,3, fB, grid2, c2, N2, 21, 80, 80, 1,1,1, 1,1,1); BNSTAGE( 4, 32, N2, unsigned short, fA);
    CONV( 5, 32, 64, 3,3,3, fA, grid2, c3, N3, 21, 80, 80, 2,2,2, 1,1,1); BNSTAGE( 5, 64, N3, unsigned short, fB);
    CONV( 6, 64, 64, 3,3,3, fB, grid3, c3, N3, 11, 40, 40, 1,1,1, 1,1,1); BNSTAGE( 6, 64, N3, unsigned short, fA);
    CONV( 7, 64, 64, 3,3,3, fA, grid3, c3, N3, 11, 40, 40, 1,1,1, 1,1,1); BNSTAGE( 7, 64, N3, unsigned short, fB);
    CONV( 8, 64, 64, 3,3,3, fB, grid3, c4, N4, 11, 40, 40, 2,2,2, 0,1,1); BNSTAGE( 8, 64, N4, unsigned short, fA);
    CONV( 9, 64, 64, 3,3,3, fA, grid4, c4, N4,  5, 20, 20, 1,1,1, 1,1,1); BNSTAGE( 9, 64, N4, unsigned short, fB);
    CONV(10, 64, 64, 3,3,3, fB, grid4, c4, N4,  5, 20, 20, 1,1,1, 1,1,1); BNSTAGE(10, 64, N4, unsigned short, fA);
    CONV(11, 64,128, 3,1,1, fA, grid4, c5, N5,  5, 20, 20, 2,1,1, 0,0,0); BNSTAGE(11, 128, N5, float, (float*)d_out);
#undef CONV
#undef BNSTAGE
}

// Round 4
// 621.987 us; speedup vs baseline: 4.9986x; 1.1798x over previous
//
#include <hip/hip_runtime.h>
#include <hip/hip_bf16.h>

// ---------------------------------------------------------------------------
// VoxelBackBone8x, R4: bf16 MFMA implicit-GEMM sparse conv, latency-pipelined.
// R3 was latency-bound (MfmaUtil 3%, 27 serial grid->feat->MFMA chains/wave).
// R4: (1) precompute all tap indices upfront (27 independent loads, one
// latency round), (2) depth-1 prefetch of the A-gather across taps,
// (3) BN stats fused into conv epilogue (shfl quad-reduce -> LDS -> 1 atomic
// per channel per block), (4) scatter/prep fused into single dispatches.
// Verified MFMA layouts (learn_hip m89/m91):
//   A[m=lane&15][k=quad*8+j], B[n=lane&15][k=quad*8+j],
//   C/D col=lane&15, row=quad*4+reg.
// ---------------------------------------------------------------------------

typedef __attribute__((ext_vector_type(8))) short bf16x8;
typedef __attribute__((ext_vector_type(4))) float f32x4;

__device__ inline unsigned short f2bf(float f) {
    unsigned u = __builtin_bit_cast(unsigned, f);
    u += 0x7FFFu + ((u >> 16) & 1u);
    return (unsigned short)(u >> 16);
}

struct ScatterArgs {
    const int* coords[4];
    int* grid[4];
    int n[4];
    int D[4], H[4], W[4];
};

__global__ __launch_bounds__(256) void scatter_grid_all(ScatterArgs a) {
    const int l = blockIdx.y;
    const int i = blockIdx.x * 256 + threadIdx.x;
    if (i >= a.n[l]) return;
    const int* c = a.coords[l] + 4 * i;
    a.grid[l][((c[0] * a.D[l] + c[1]) * a.H[l] + c[2]) * a.W[l] + c[3]] = i;
}

struct PrepArgs {
    const float* src[11];
    unsigned short* dst[11];
    int T[11], CIN[11], COUT[11], total[11];   // total = (T+1)*CIN*COUT
};

// fp32 [t][cin][cout] -> bf16 [t][cout][cin]; pad tap T zeroed
__global__ __launch_bounds__(256) void prep_w_all(PrepArgs a) {
    const int l = blockIdx.y;
    const int i = blockIdx.x * 256 + threadIdx.x;
    if (i >= a.total[l]) return;
    const int COUT = a.COUT[l], CIN = a.CIN[l], T = a.T[l];
    const int co = i % COUT; const int r = i / COUT; const int ci = r % CIN; const int t = r / CIN;
    unsigned short v = (t < T) ? f2bf(a.src[l][i]) : (unsigned short)0;
    a.dst[l][((size_t)t * COUT + co) * CIN + ci] = v;
}

// Layer 0: CIN=4 -> COUT=16, k=3, stride 1, pad 1, fp32 VALU
__global__ __launch_bounds__(256) void sp_conv0(const float* __restrict__ fin,
                                                const int* __restrict__ grid,
                                                const int* __restrict__ oc, int n_out,
                                                const float* __restrict__ w,
                                                float* __restrict__ out,
                                                int D, int H, int W) {
    const int c = threadIdx.x & 15;
    const int p = (blockIdx.x * 256 + threadIdx.x) >> 4;
    if (p >= n_out) return;
    const int b   = oc[4*p+0];
    const int iz0 = oc[4*p+1] - 1;
    const int iy0 = oc[4*p+2] - 1;
    const int ix0 = oc[4*p+3] - 1;
    const int* gb = grid + b * (D * H * W);
    float acc = 0.f;
    for (int kd = 0; kd < 3; ++kd) {
        const int iz = iz0 + kd;
        if ((unsigned)iz >= (unsigned)D) continue;
        for (int kh = 0; kh < 3; ++kh) {
            const int iy = iy0 + kh;
            if ((unsigned)iy >= (unsigned)H) continue;
            for (int kw = 0; kw < 3; ++kw) {
                const int ix = ix0 + kw;
                if ((unsigned)ix >= (unsigned)W) continue;
                const int idx = gb[(iz*H + iy)*W + ix];
                if (idx < 0) continue;
                const float4 v = *(const float4*)(fin + (size_t)idx * 4);
                const float* wp = w + (size_t)((kd*3 + kh)*3 + kw) * 4 * 16 + c;
                acc = fmaf(v.x, wp[0],  acc);
                acc = fmaf(v.y, wp[16], acc);
                acc = fmaf(v.z, wp[32], acc);
                acc = fmaf(v.w, wp[48], acc);
            }
        }
    }
    out[(size_t)p*16 + c] = acc;
}

template<int CIN, int COUT, int KD, int KH, int KW>
__global__ __launch_bounds__(256) void sp_conv_mfma(
    const unsigned short* __restrict__ fin, const int* __restrict__ grid,
    const int* __restrict__ oc, int n_out,
    const unsigned short* __restrict__ wt, float* __restrict__ out,
    float* __restrict__ stats,
    int D, int H, int W, int sz, int sy, int sx, int pz, int py, int px)
{
    constexpr int T  = KD*KH*KW;
    constexpr int NT = COUT/16;
    __shared__ float ls[2*COUT];
    const int lane = threadIdx.x & 63;
    const int wid  = threadIdx.x >> 6;
    const int n    = lane & 15;
    const int quad = lane >> 4;
    const int pbase = blockIdx.x * 64 + wid * 16;

    if (threadIdx.x < 2*COUT) ls[threadIdx.x] = 0.f;

    int pc = pbase + n;
    if (pc > n_out - 1) pc = n_out - 1;
    const int4 cc = ((const int4*)oc)[pc];
    const int* gb = grid + cc.x * (D * H * W);
    const int iz0 = cc.y * sz - pz;
    const int iy0 = cc.z * sy - py;
    const int ix0 = cc.w * sx - px;

    f32x4 acc[NT];
#pragma unroll
    for (int t = 0; t < NT; ++t) acc[t] = (f32x4){0.f, 0.f, 0.f, 0.f};

    if constexpr (CIN >= 32) {
        constexpr int S = CIN/32;
        // --- all tap indices upfront: independent loads, one latency round
        int idx[T];
#pragma unroll
        for (int tap = 0; tap < T; ++tap) {
            const int kd = tap/(KH*KW), kr = tap%(KH*KW), kh = kr/KW, kw = kr%KW;
            const int iz = iz0 + kd, iy = iy0 + kh, ix = ix0 + kw;
            idx[tap] = ((unsigned)iz < (unsigned)D && (unsigned)iy < (unsigned)H &&
                        (unsigned)ix < (unsigned)W) ? gb[(iz*H + iy)*W + ix] : -1;
        }
        // --- depth-1 pipelined A gather
        bf16x8 aC[S], aN[S];
#pragma unroll
        for (int s = 0; s < S; ++s) {
            aC[s] = (bf16x8){};
            if (idx[0] >= 0)
                aC[s] = *(const bf16x8*)(fin + (size_t)idx[0]*CIN + s*32 + quad*8);
        }
#pragma unroll
        for (int tap = 0; tap < T; ++tap) {
            if (tap + 1 < T) {
#pragma unroll
                for (int s = 0; s < S; ++s) {
                    aN[s] = (bf16x8){};
                    if (idx[tap+1] >= 0)
                        aN[s] = *(const bf16x8*)(fin + (size_t)idx[tap+1]*CIN + s*32 + quad*8);
                }
            }
            const unsigned short* wrow = wt + (size_t)tap*(COUT*CIN) + n*CIN + quad*8;
#pragma unroll
            for (int s = 0; s < S; ++s)
#pragma unroll
                for (int t = 0; t < NT; ++t) {
                    bf16x8 b = *(const bf16x8*)(wrow + (size_t)(t*16)*CIN + s*32);
                    acc[t] = __builtin_amdgcn_mfma_f32_16x16x32_bf16(aC[s], b, acc[t], 0, 0, 0);
                }
#pragma unroll
            for (int s = 0; s < S; ++s) aC[s] = aN[s];
        }
    } else {  // CIN == 16: 2 taps packed per K=32 (quad>>1 picks the tap)
        constexpr int KB = (T + 1) / 2;
        int idx[KB], tcv[KB];
        const int cinb = (quad & 1) * 8;
#pragma unroll
        for (int kb = 0; kb < KB; ++kb) {
            const int tap = 2*kb + (quad >> 1);
            const bool tv = (tap < T);
            const int td = tv ? tap : 0;
            const int kd = td/(KH*KW), kr = td%(KH*KW), kh = kr/KW, kw = kr%KW;
            const int iz = iz0 + kd, iy = iy0 + kh, ix = ix0 + kw;
            idx[kb] = (tv && (unsigned)iz < (unsigned)D && (unsigned)iy < (unsigned)H &&
                       (unsigned)ix < (unsigned)W) ? gb[(iz*H + iy)*W + ix] : -1;
            tcv[kb] = tv ? tap : T;   // pad slot zeroed by prep
        }
        bf16x8 aC = {}, aN;
        if (idx[0] >= 0) aC = *(const bf16x8*)(fin + (size_t)idx[0]*16 + cinb);
#pragma unroll
        for (int kb = 0; kb < KB; ++kb) {
            if (kb + 1 < KB) {
                aN = (bf16x8){};
                if (idx[kb+1] >= 0) aN = *(const bf16x8*)(fin + (size_t)idx[kb+1]*16 + cinb);
            }
#pragma unroll
            for (int t = 0; t < NT; ++t) {
                bf16x8 b = *(const bf16x8*)(wt + ((size_t)tcv[kb]*COUT + t*16 + n)*16 + cinb);
                acc[t] = __builtin_amdgcn_mfma_f32_16x16x32_bf16(aC, b, acc[t], 0, 0, 0);
            }
            aC = aN;
        }
    }

    // --- store raw fp32
#pragma unroll
    for (int t = 0; t < NT; ++t)
#pragma unroll
        for (int r = 0; r < 4; ++r) {
            const int p = pbase + quad*4 + r;
            if (p < n_out) out[(size_t)p * COUT + t*16 + n] = acc[t][r];
        }

    // --- fused BN stats: quad shuffle-reduce -> LDS -> 1 atomic/ch/block
    __syncthreads();
#pragma unroll
    for (int t = 0; t < NT; ++t) {
        float s1 = 0.f, s2 = 0.f;
#pragma unroll
        for (int r = 0; r < 4; ++r) {
            const int p = pbase + quad*4 + r;
            if (p < n_out) { const float v = acc[t][r]; s1 += v; s2 += v*v; }
        }
        s1 += __shfl_xor(s1, 16); s2 += __shfl_xor(s2, 16);
        s1 += __shfl_xor(s1, 32); s2 += __shfl_xor(s2, 32);
        if (quad == 0) {
            atomicAdd(&ls[t*16 + n], s1);
            atomicAdd(&ls[COUT + t*16 + n], s2);
        }
    }
    __syncthreads();
    if (threadIdx.x < 2*COUT) atomicAdd(&stats[threadIdx.x], ls[threadIdx.x]);
}

template<int C>
__global__ __launch_bounds__(256) void reduce_stats(const float* __restrict__ x, int nn,
                                                    float* __restrict__ stats)
{
    constexpr int R = 256 / C;
    __shared__ float s1[256];
    __shared__ float s2[256];
    const int c = threadIdx.x % C;
    const int r = threadIdx.x / C;
    float a1 = 0.f, a2 = 0.f;
    for (int i = blockIdx.x * R + r; i < nn; i += R * gridDim.x) {
        float v = x[(size_t)i*C + c];
        a1 += v;
        a2 += v * v;
    }
    s1[threadIdx.x] = a1;
    s2[threadIdx.x] = a2;
    __syncthreads();
    for (int off = 128; off >= C; off >>= 1) {
        if (threadIdx.x < off) {
            s1[threadIdx.x] += s1[threadIdx.x + off];
            s2[threadIdx.x] += s2[threadIdx.x + off];
        }
        __syncthreads();
    }
    if (threadIdx.x < C) {
        atomicAdd(&stats[c],     s1[threadIdx.x]);
        atomicAdd(&stats[C + c], s2[threadIdx.x]);
    }
}

__device__ inline void stv(float* p, float v)          { *p = v; }
__device__ inline void stv(unsigned short* p, float v) { *p = f2bf(v); }

template<int C, typename OUT>
__global__ __launch_bounds__(256) void bn_relu_apply(const float* __restrict__ x,
                                                     OUT* __restrict__ y, int nn,
                                                     const float* __restrict__ stats,
                                                     const float* __restrict__ gamma,
                                                     const float* __restrict__ beta)
{
    const size_t i = (size_t)blockIdx.x * blockDim.x + threadIdx.x;
    if (i >= (size_t)nn * C) return;
    const int c = (int)(i % C);
    const float inv_n = 1.f / (float)nn;
    const float mu  = stats[c] * inv_n;
    const float var = stats[C + c] * inv_n - mu * mu;
    const float g = gamma[c] * rsqrtf(var + 1e-3f);
    const float v = (x[i] - mu) * g + beta[c];
    stv(y + i, v > 0.f ? v : 0.f);
}

extern "C" void kernel_launch(void* const* d_in, const int* in_sizes, int n_in,
                              void* d_out, int out_size, void* d_ws, size_t ws_size,
                              hipStream_t stream) {
    const float* WPTR[12] = {
        (const float*)d_in[1], (const float*)d_in[2], (const float*)d_in[3],
        (const float*)d_in[4], (const float*)d_in[5], (const float*)d_in[6],
        (const float*)d_in[7], (const float*)d_in[8], (const float*)d_in[9],
        (const float*)d_in[10], (const float*)d_in[11], (const float*)d_in[12] };
    const float* vf    = (const float*)d_in[0];
    const float* gamma = (const float*)d_in[13];
    const float* beta  = (const float*)d_in[14];
    const int* c1 = (const int*)d_in[15];
    const int* c2 = (const int*)d_in[16];
    const int* c3 = (const int*)d_in[17];
    const int* c4 = (const int*)d_in[18];
    const int* c5 = (const int*)d_in[19];
    const int N1 = in_sizes[15] / 4;
    const int N2 = in_sizes[16] / 4;
    const int N3 = in_sizes[17] / 4;
    const int N4 = in_sizes[18] / 4;
    const int N5 = in_sizes[19] / 4;

    static const int LT[12]  = {27,27,27,27,27,27,27,27,27,27,27,3};
    static const int LCI[12] = {4,16,16,32,32,32,64,64,64,64,64,64};
    static const int LCO[12] = {16,16,32,32,32,64,64,64,64,64,64,128};

    const size_t G1 = (size_t)2*41*160*160;
    const size_t G2 = (size_t)2*21*80*80;
    const size_t G3 = (size_t)2*11*40*40;
    const size_t G4 = (size_t)2*5*20*20;
    int* grid1 = (int*)d_ws;
    int* grid2 = grid1 + G1;
    int* grid3 = grid2 + G2;
    int* grid4 = grid3 + G3;
    float* stats = (float*)(grid4 + G4);            // 12 x 256 floats

    size_t maxE = (size_t)N1*16;
    if ((size_t)N2*32  > maxE) maxE = (size_t)N2*32;
    if ((size_t)N3*64  > maxE) maxE = (size_t)N3*64;
    if ((size_t)N4*64  > maxE) maxE = (size_t)N4*64;
    if ((size_t)N5*128 > maxE) maxE = (size_t)N5*128;
    maxE = (maxE + 7) & ~(size_t)7;

    float* raw = stats + 12*256;                    // fp32 conv output
    unsigned short* fA = (unsigned short*)(raw + maxE);
    unsigned short* fB = fA + maxE;
    unsigned short* wtb = fB + maxE;                // bf16 transposed weights
    size_t wtoff[12];
    {
        size_t o = 0;
        for (int i = 1; i < 12; ++i) {
            wtoff[i] = o;
            o += (size_t)(LT[i] + 1) * LCI[i] * LCO[i];
        }
    }

    hipMemsetAsync(grid1, 0xFF, (G1+G2+G3+G4)*sizeof(int), stream);
    hipMemsetAsync(stats, 0, 12*256*sizeof(float), stream);

    {
        ScatterArgs sa;
        sa.coords[0]=c1; sa.coords[1]=c2; sa.coords[2]=c3; sa.coords[3]=c4;
        sa.grid[0]=grid1; sa.grid[1]=grid2; sa.grid[2]=grid3; sa.grid[3]=grid4;
        sa.n[0]=N1; sa.n[1]=N2; sa.n[2]=N3; sa.n[3]=N4;
        sa.D[0]=41; sa.H[0]=160; sa.W[0]=160;
        sa.D[1]=21; sa.H[1]= 80; sa.W[1]= 80;
        sa.D[2]=11; sa.H[2]= 40; sa.W[2]= 40;
        sa.D[3]= 5; sa.H[3]= 20; sa.W[3]= 20;
        int mx = N1; if (N2>mx) mx=N2; if (N3>mx) mx=N3; if (N4>mx) mx=N4;
        dim3 g((mx + 255)/256, 4);
        scatter_grid_all<<<g, 256, 0, stream>>>(sa);
    }
    {
        PrepArgs pa;
        int mx = 0;
        for (int i = 1; i < 12; ++i) {
            pa.src[i-1] = WPTR[i];
            pa.dst[i-1] = wtb + wtoff[i];
            pa.T[i-1] = LT[i]; pa.CIN[i-1] = LCI[i]; pa.COUT[i-1] = LCO[i];
            pa.total[i-1] = (LT[i]+1)*LCI[i]*LCO[i];
            if (pa.total[i-1] > mx) mx = pa.total[i-1];
        }
        dim3 g((mx + 255)/256, 11);
        prep_w_all<<<g, 256, 0, stream>>>(pa);
    }

    enum { GOFF_0 = 0, GOFF_1 = 16, GOFF_2 = 32, GOFF_3 = 64, GOFF_4 = 96, GOFF_5 = 128,
           GOFF_6 = 192, GOFF_7 = 256, GOFF_8 = 320, GOFF_9 = 384, GOFF_10 = 448, GOFF_11 = 512 };

#define APPLY(i, COUT, NP, FOUT_T, FOUT) \
    bn_relu_apply<COUT, FOUT_T><<<(((size_t)(NP)*(COUT)) + 255)/256, 256, 0, stream>>>( \
        raw, FOUT, NP, stats + (i)*256, gamma + GOFF_##i, beta + GOFF_##i);

    // L0: fp32 VALU conv + separate stats reduce
    sp_conv0<<<((size_t)N1*16 + 255)/256, 256, 0, stream>>>(vf, grid1, c1, N1, WPTR[0], raw, 41,160,160);
    { int rb = (N1 + 15)/16; if (rb > 240) rb = 240;
      reduce_stats<16><<<rb, 256, 0, stream>>>(raw, N1, stats + 0*256); }
    APPLY(0, 16, N1, unsigned short, fA);

#define CONV(i, CIN, COUT, KD,KH,KW, FIN, GRD, OC, NP, D,H,W, SZ,SY,SX, PZ,PY,PX) \
    sp_conv_mfma<CIN,COUT,KD,KH,KW><<<((NP)+63)/64, 256, 0, stream>>>( \
        FIN, GRD, OC, NP, wtb + wtoff[i], raw, stats + (i)*256, D,H,W, SZ,SY,SX, PZ,PY,PX);

    CONV( 1, 16, 16, 3,3,3, fA, grid1, c1, N1, 41,160,160, 1,1,1, 1,1,1); APPLY( 1, 16, N1, unsigned short, fB);
    CONV( 2, 16, 32, 3,3,3, fB, grid1, c2, N2, 41,160,160, 2,2,2, 1,1,1); APPLY( 2, 32, N2, unsigned short, fA);
    CONV( 3, 32, 32, 3,3,3, fA, grid2, c2, N2, 21, 80, 80, 1,1,1, 1,1,1); APPLY( 3, 32, N2, unsigned short, fB);
    CONV( 4, 32, 32, 3,3,3, fB, grid2, c2, N2, 21, 80, 80, 1,1,1, 1,1,1); APPLY( 4, 32, N2, unsigned short, fA);
    CONV( 5, 32, 64, 3,3,3, fA, grid2, c3, N3, 21, 80, 80, 2,2,2, 1,1,1); APPLY( 5, 64, N3, unsigned short, fB);
    CONV( 6, 64, 64, 3,3,3, fB, grid3, c3, N3, 11, 40, 40, 1,1,1, 1,1,1); APPLY( 6, 64, N3, unsigned short, fA);
    CONV( 7, 64, 64, 3,3,3, fA, grid3, c3, N3, 11, 40, 40, 1,1,1, 1,1,1); APPLY( 7, 64, N3, unsigned short, fB);
    CONV( 8, 64, 64, 3,3,3, fB, grid3, c4, N4, 11, 40, 40, 2,2,2, 0,1,1); APPLY( 8, 64, N4, unsigned short, fA);
    CONV( 9, 64, 64, 3,3,3, fA, grid4, c4, N4,  5, 20, 20, 1,1,1, 1,1,1); APPLY( 9, 64, N4, unsigned short, fB);
    CONV(10, 64, 64, 3,3,3, fB, grid4, c4, N4,  5, 20, 20, 1,1,1, 1,1,1); APPLY(10, 64, N4, unsigned short, fA);
    CONV(11, 64,128, 3,1,1, fA, grid4, c5, N5,  5, 20, 20, 2,1,1, 0,0,0); APPLY(11, 128, N5, float, (float*)d_out);
#undef CONV
#undef APPLY
}